// Round 5
// baseline (93955.115 us; speedup 1.0000x reference)
//
#include <hip/hip_runtime.h>
#include <hip/hip_bf16.h>
#include <cstdint>

// LSTM, T=32768 steps, C=512, I=1024 (x 512 | h 512), fp32.
//   1) gx[t][*] = Wx @ x_t + b  -- parallel GEMM over all timesteps (chunked in ws)
//   2) serial recurrence: 128 blocks x 256 threads, each block owns 4 (c,h) rows;
//      block's Wh slice (16 gate-rows x 512 = 32 KB) staged in LDS once per launch
//      (VGPR pinning failed twice: allocator spills -> LDS is deterministic).
//      Per-step sync: TAGGED-WORD mailbox -- each h word published as ONE u64
//      atomicExch (tag<<32 | value). Readers poll the data word itself until
//      tag==t; value rides in the same 8B. No flags, no fences, no 2nd round trip.

#define T_TOTAL 32768
#define NBLK 128

__device__ __forceinline__ float sigm(float x) {
    return 1.0f / (1.0f + __expf(-x));
}
__device__ __forceinline__ float tanh_fast(float x) {
    float ax = fabsf(x);
    float e = __expf(2.0f * ax);          // +inf for large ax is fine -> t = 1
    float t = 1.0f - 2.0f / (e + 1.0f);
    return copysignf(t, x);
}

// ---------------------------------------------------------------------------
// GEMM: gx word index for fused row jg (0..511), gate g:
//   obase = (jg>>2)*16 + g*4 + (jg&3)   -- block-major for 128 4-row blocks.
// ---------------------------------------------------------------------------
__global__ __launch_bounds__(256, 1) void lstm_gemm_x(
    const float* __restrict__ x,
    const float* __restrict__ wf, const float* __restrict__ wi,
    const float* __restrict__ wc, const float* __restrict__ wo,
    const float* __restrict__ bf, const float* __restrict__ bi,
    const float* __restrict__ bc, const float* __restrict__ bo,
    float* __restrict__ gx, int t0, int tend)
{
    __shared__ float xs[16][512];
    const int tid = threadIdx.x;
    const int tt0 = t0 + blockIdx.x * 16;
    const int j0  = blockIdx.y * 128;

    #pragma unroll
    for (int i = 0; i < 8; ++i) {
        int idx  = tid + i * 256;
        int trow = idx >> 7, kq = idx & 127;
        int t    = tt0 + trow;
        float4 v = make_float4(0.f, 0.f, 0.f, 0.f);
        if (t < tend) v = *(const float4*)(x + (size_t)t * 512 + kq * 4);
        *(float4*)&xs[trow][kq * 4] = v;
    }
    __syncthreads();

    const int j  = j0 + (tid & 127);
    const int th = tid >> 7;
    const int g  = j >> 9;
    const int jg = j & 511;
    const float* Wg = (g == 0) ? wf : (g == 1) ? wi : (g == 2) ? wc : wo;
    const float* Bg = (g == 0) ? bf : (g == 1) ? bi : (g == 2) ? bc : bo;
    const float* wrow = Wg + (size_t)jg * 1024;

    float acc[8];
    #pragma unroll
    for (int i = 0; i < 8; ++i) acc[i] = 0.f;

    for (int k = 0; k < 512; k += 4) {
        float4 w4 = *(const float4*)(wrow + k);
        #pragma unroll
        for (int tt = 0; tt < 8; ++tt) {
            float4 x4 = *(const float4*)&xs[th * 8 + tt][k];
            acc[tt] = fmaf(w4.x, x4.x, acc[tt]);
            acc[tt] = fmaf(w4.y, x4.y, acc[tt]);
            acc[tt] = fmaf(w4.z, x4.z, acc[tt]);
            acc[tt] = fmaf(w4.w, x4.w, acc[tt]);
        }
    }

    const float bias = Bg[jg];
    const int   obase = (jg >> 2) * 16 + g * 4 + (jg & 3);
    #pragma unroll
    for (int tt = 0; tt < 8; ++tt) {
        int t = tt0 + th * 8 + tt;
        if (t < tend) gx[(size_t)(t - t0) * 2048 + obase] = acc[tt] + bias;
    }
}

// ---------------------------------------------------------------------------
// Serial recurrence. 128 blocks x 256 threads (all co-resident on 256 CUs).
// Thread map: tid = r*64 + g*16 + seg (r=row 0..3, g=gate, seg=k-16th of 32).
// Tagged mailbox per step t: publisher (lane 0 of each wave) atomicExch's
//   hdq[t&1][b*4+r] = ((t+1)<<32)|bits(h). Reader at step t polls its 2 words
//   of hdq[(t&1)^1] until tag==t (t=0 satisfied by zero-init), stages to LDS.
// Slot reuse safe: word w gets tag t+2 only after its owner observed ALL tag-t+1
//   words, which happen-after every block's tag-t polls (incl. this reader's)
//   succeeded. Same-slot tags share parity -> poll can use exact equality.
// One barrier/step: h staged into parity-alternating LDS buffer, so stragglers
//   in dot(t) never collide with leaders staging t+1 (different buffer), and
//   leaders can't reach stage(t+2) without all waves passing barrier(t+1).
// ---------------------------------------------------------------------------
__global__ __launch_bounds__(256, 1) void lstm_serial(
    const float* __restrict__ wf, const float* __restrict__ wi,
    const float* __restrict__ wc, const float* __restrict__ wo,
    const float* __restrict__ gx,
    unsigned long long* __restrict__ hdq,   // [2][512] tagged h words
    float* __restrict__ cstate,
    int t0, int steps, float* __restrict__ out)
{
    __shared__ alignas(16) float4 wlds[2048];   // [16 gate-rows][128 f4] = 32 KB
    __shared__ alignas(16) float  hl[2][512];   // parity-double-buffered h
    const int b   = blockIdx.x;            // 0..127
    const int tid = threadIdx.x;
    const int r   = tid >> 6;              // 0..3 (wave index = row)
    const int g   = (tid >> 4) & 3;        // gate
    const int seg = tid & 15;              // k-segment (32 floats each)

    // stage this block's Wh slice: rows b*4..b*4+3, 4 gates, h-part cols 512..1023
    #pragma unroll
    for (int k = 0; k < 8; ++k) {
        int idx   = k * 256 + tid;         // 0..2047 float4s
        int row16 = idx >> 7, q = idx & 127;
        int gg    = row16 >> 2, rr = row16 & 3;
        const float* Wp = (gg == 0) ? wf : (gg == 1) ? wi : (gg == 2) ? wc : wo;
        wlds[idx] = ((const float4*)(Wp + (size_t)(b * 4 + rr) * 1024 + 512))[q];
    }
    float cold = cstate[b * 4 + r];
    __syncthreads();

    const int wbase = (g * 4 + r) * 128 + seg * 8;
    const int hbase = seg * 8;
    const int sw    = seg & 7;             // read-order rotation: 8 words/bank (min)

    for (int s = 0; s < steps; ++s) {
        const int t  = t0 + s;
        const int sp = (t & 1) ^ 1;        // slot holding h_{t-1}
        const int sc = t & 1;              // slot receiving h_t

        // gx for this step (MALL-resident: GEMM wrote it just before); 16-lane broadcast
        const float gxv = gx[(size_t)s * 2048 + (b << 4) + (g << 2) + r];

        // poll my 2 tagged words of h_{t-1}; value rides with the tag
        const unsigned long long* src = hdq + (size_t)sp * 512 + 2 * tid;
        const unsigned need = (unsigned)t;
        unsigned long long d0, d1;
        int guard = 0;
        do {
            d0 = __hip_atomic_load(src,     __ATOMIC_RELAXED, __HIP_MEMORY_SCOPE_AGENT);
            d1 = __hip_atomic_load(src + 1, __ATOMIC_RELAXED, __HIP_MEMORY_SCOPE_AGENT);
        } while (((unsigned)(d0 >> 32) != need || (unsigned)(d1 >> 32) != need)
                 && ++guard < (1 << 20));
        hl[sp][2 * tid]     = __uint_as_float((unsigned)d0);
        hl[sp][2 * tid + 1] = __uint_as_float((unsigned)d1);
        __syncthreads();                   // h_{t-1} fully staged (single barrier/step)

        // 32-float dot vs LDS weights; rotated order keeps LDS at 8 words/bank
        const float4* h4 = (const float4*)hl[sp];
        float4 av = make_float4(0.f, 0.f, 0.f, 0.f);
        #pragma unroll
        for (int j = 0; j < 8; ++j) {
            int q = j ^ sw;
            float4 wv = wlds[wbase + q];
            float4 hv = h4[hbase + q];
            av.x = fmaf(wv.x, hv.x, av.x);
            av.y = fmaf(wv.y, hv.y, av.y);
            av.z = fmaf(wv.z, hv.z, av.z);
            av.w = fmaf(wv.w, hv.w, av.w);
        }
        float acc = (av.x + av.y) + (av.z + av.w);
        acc += __shfl_xor(acc, 1);
        acc += __shfl_xor(acc, 2);
        acc += __shfl_xor(acc, 4);
        acc += __shfl_xor(acc, 8);
        if (seg == 0) acc += gxv;          // lanes 0,16,32,48 hold gates f,i,c,o

        float gf = __shfl(acc, 0);
        float gi = __shfl(acc, 16);
        float gc = __shfl(acc, 32);
        float go = __shfl(acc, 48);

        float ff  = sigm(gf);
        float iiv = sigm(gi);
        float ccv = tanh_fast(gc);
        float ov  = sigm(go);
        cold = fmaf(ff, cold, iiv * ccv);
        float hnew = tanh_fast(cold) * ov;

        if ((tid & 63) == 0) {             // wave leader publishes its tagged word
            unsigned long long tv = ((unsigned long long)(need + 1) << 32)
                                  | (unsigned long long)__float_as_uint(hnew);
            atomicExch(hdq + (size_t)sc * 512 + b * 4 + r, tv);
            if (t == T_TOTAL - 1) {
                out[b * 4 + r]       = cold;
                out[512 + b * 4 + r] = hnew;
            }
        }
    }

    if ((tid & 63) == 0) cstate[b * 4 + r] = cold;
}

// ---------------------------------------------------------------------------
extern "C" void kernel_launch(void* const* d_in, const int* in_sizes, int n_in,
                              void* d_out, int out_size, void* d_ws, size_t ws_size,
                              hipStream_t stream)
{
    const float* x  = (const float*)d_in[0];
    const float* wf = (const float*)d_in[1];
    const float* bf = (const float*)d_in[2];
    const float* wi = (const float*)d_in[3];
    const float* bi = (const float*)d_in[4];
    const float* wc = (const float*)d_in[5];
    const float* bc = (const float*)d_in[6];
    const float* wo = (const float*)d_in[7];
    const float* bo = (const float*)d_in[8];
    float* out = (float*)d_out;

    char* wsb = (char*)d_ws;
    unsigned long long* hdq = (unsigned long long*)wsb;      // 2*512*8 = 8192 B
    float* cst = (float*)(wsb + 8192);                       // 512*4   = 2048 B
    const size_t metaBytes = 8192 + 2048;                    // 10240 (16B aligned)
    float* gxbuf = (float*)(wsb + metaBytes);

    size_t gxCapSteps = (ws_size > metaBytes)
                        ? (ws_size - metaBytes) / (2048 * sizeof(float)) : 0;
    int CH = (gxCapSteps < (size_t)T_TOTAL) ? (int)gxCapSteps : T_TOTAL;
    CH &= ~15;
    if (CH < 16) CH = 16;

    hipMemsetAsync(wsb, 0, metaBytes, stream);   // tags=0 (t=0 poll passes), c=0, h=0

    for (int t0 = 0; t0 < T_TOTAL; t0 += CH) {
        int tend  = t0 + CH; if (tend > T_TOTAL) tend = T_TOTAL;
        int steps = tend - t0;
        dim3 ggrid((steps + 15) / 16, 16);
        lstm_gemm_x<<<ggrid, 256, 0, stream>>>(x, wf, wi, wc, wo,
                                               bf, bi, bc, bo, gxbuf, t0, tend);
        lstm_serial<<<NBLK, 256, 0, stream>>>(wf, wi, wc, wo, gxbuf,
                                              hdq, cst, t0, steps, out);
    }
}

// Round 6
// 68628.931 us; speedup vs baseline: 1.3690x; 1.3690x over previous
//
#include <hip/hip_runtime.h>
#include <hip/hip_bf16.h>
#include <cstdint>

// LSTM, T=32768 steps, C=512, I=1024 (x 512 | h 512), fp32.
//   1) gx[t][*] = Wx @ x_t + b  -- parallel GEMM over all timesteps (chunked in ws)
//   2) serial recurrence: 64 blocks x 256 threads; block owns 8 (c,h) rows; its
//      Wh slice (8 rows x 4 gates x 512 = 64 KB) lives in static LDS.
//      Thread (r,seg): all 4 gates over a 16-float k-chunk; 5x shfl_xor reduce.
//      Sync: tagged-word mailbox (u64 atomicExch, tag<<32|h). ONLY WAVE 0 polls
//      (4096 pollers device-wide, was 32768 in R5 -> MALL contention collapse).
//      LDS reads use q = j ^ ((seg>>1)&3) swizzle -> conflict-free per 8-lane group.

#define T_TOTAL 32768
#define NBLK 64

__device__ __forceinline__ float sigm(float x) {
    return 1.0f / (1.0f + __expf(-x));
}
__device__ __forceinline__ float tanh_fast(float x) {
    float ax = fabsf(x);
    float e = __expf(2.0f * ax);          // +inf for large ax is fine -> t = 1
    float t = 1.0f - 2.0f / (e + 1.0f);
    return copysignf(t, x);
}

// ---------------------------------------------------------------------------
// GEMM: for fused row jg (c-row), gate g: block b = jg>>3, r = jg&7:
//   gx word = (jg>>3)*32 + (jg&7)*4 + g   (block-major, float4 per (b,r))
// ---------------------------------------------------------------------------
__global__ __launch_bounds__(256, 1) void lstm_gemm_x(
    const float* __restrict__ x,
    const float* __restrict__ wf, const float* __restrict__ wi,
    const float* __restrict__ wc, const float* __restrict__ wo,
    const float* __restrict__ bf, const float* __restrict__ bi,
    const float* __restrict__ bc, const float* __restrict__ bo,
    float* __restrict__ gx, int t0, int tend)
{
    __shared__ float xs[16][512];
    const int tid = threadIdx.x;
    const int tt0 = t0 + blockIdx.x * 16;
    const int j0  = blockIdx.y * 128;

    #pragma unroll
    for (int i = 0; i < 8; ++i) {
        int idx  = tid + i * 256;
        int trow = idx >> 7, kq = idx & 127;
        int t    = tt0 + trow;
        float4 v = make_float4(0.f, 0.f, 0.f, 0.f);
        if (t < tend) v = *(const float4*)(x + (size_t)t * 512 + kq * 4);
        *(float4*)&xs[trow][kq * 4] = v;
    }
    __syncthreads();

    const int j  = j0 + (tid & 127);
    const int th = tid >> 7;
    const int g  = j >> 9;
    const int jg = j & 511;
    const float* Wg = (g == 0) ? wf : (g == 1) ? wi : (g == 2) ? wc : wo;
    const float* Bg = (g == 0) ? bf : (g == 1) ? bi : (g == 2) ? bc : bo;
    const float* wrow = Wg + (size_t)jg * 1024;

    float acc[8];
    #pragma unroll
    for (int i = 0; i < 8; ++i) acc[i] = 0.f;

    for (int k = 0; k < 512; k += 4) {
        float4 w4 = *(const float4*)(wrow + k);
        #pragma unroll
        for (int tt = 0; tt < 8; ++tt) {
            float4 x4 = *(const float4*)&xs[th * 8 + tt][k];
            acc[tt] = fmaf(w4.x, x4.x, acc[tt]);
            acc[tt] = fmaf(w4.y, x4.y, acc[tt]);
            acc[tt] = fmaf(w4.z, x4.z, acc[tt]);
            acc[tt] = fmaf(w4.w, x4.w, acc[tt]);
        }
    }

    const float bias = Bg[jg];
    const int   obase = (jg >> 3) * 32 + (jg & 7) * 4 + g;
    #pragma unroll
    for (int tt = 0; tt < 8; ++tt) {
        int t = tt0 + th * 8 + tt;
        if (t < tend) gx[(size_t)(t - t0) * 2048 + obase] = acc[tt] + bias;
    }
}

// ---------------------------------------------------------------------------
// Serial recurrence. 64 blocks x 256 threads (1 block/CU, all co-resident).
// Thread map: tid = r*32 + seg  (r = row 0..7, seg = 16-float k-chunk 0..31).
// Per step t (sp = slot of h_{t-1}, sc = slot receiving h_t):
//   prefetch: 16 w-float4 -> regs (swizzled, conflict-free), gx4 (seg==0).
//   wave 0:  poll 8 tagged u64/lane until all tags==t (batched loads ~1 RTT),
//            unpack low words -> hl[sp].  Others wait at the barrier.
//   barrier; dot (4 gates x 16 floats vs hl); 5x shfl_xor reduce per gate;
//   seg==0:  activations, c/h update, ONE u64 atomicExch publish (tag t+1).
// Slot-reuse safety: block overwrites a word of h_{t-1} (tag t) with h_{t+1}
//   (tag t+2) only after its step-t poll saw tag t+1 on ALL h_t words; each
//   such publish happen-after that block consumed h_{t-1}. 8B atomic => no tears.
// Single barrier/step is safe: __syncthreads drains each wave's own lgkmcnt,
//   and hl is parity-double-buffered.
// ---------------------------------------------------------------------------
__global__ __launch_bounds__(256, 1) void lstm_serial(
    const float* __restrict__ wf, const float* __restrict__ wi,
    const float* __restrict__ wc, const float* __restrict__ wo,
    const float* __restrict__ gx,
    unsigned long long* __restrict__ hdq,   // [2][512] tagged h words
    float* __restrict__ cstate,
    int t0, int steps, float* __restrict__ out)
{
    __shared__ alignas(16) float4 wlds4[4096];   // [r*4+g][128 f4] = 64 KB
    __shared__ alignas(16) float  hl[2][512];    // parity-double-buffered h (4 KB)
    const int b   = blockIdx.x;            // 0..63
    const int tid = threadIdx.x;
    const int r   = tid >> 5;              // 0..7
    const int seg = tid & 31;              // 0..31

    // stage Wh slice: (r,g) row-pair-major, h-part cols 512..1023
    #pragma unroll
    for (int k = 0; k < 16; ++k) {
        int idx = k * 256 + tid;           // 0..4095 float4s
        int rg  = idx >> 7, q = idx & 127;
        int rr  = rg >> 2, gg = rg & 3;
        const float* Wp = (gg == 0) ? wf : (gg == 1) ? wi : (gg == 2) ? wc : wo;
        wlds4[idx] = ((const float4*)(Wp + (size_t)(b * 8 + rr) * 1024 + 512))[q];
    }
    float cold = cstate[b * 8 + r];        // only seg==0's copy is used
    __syncthreads();

    const int swz = (seg >> 1) & 3;        // bank swizzle within 8-lane group
    const float4* hl4 = (const float4*)hl;

    for (int s = 0; s < steps; ++s) {
        const int t  = t0 + s;
        const int sp = (t & 1) ^ 1;        // slot holding h_{t-1}
        const int sc = t & 1;              // slot receiving h_t

        // gx prefetch (only consumed by seg==0 lanes)
        float4 gx4 = make_float4(0.f, 0.f, 0.f, 0.f);
        if (seg == 0)
            gx4 = *(const float4*)(gx + (size_t)s * 2048 + b * 32 + r * 4);

        // weight prefetch into regs (issues during the poll window)
        float4 wv0[4], wv1[4], wv2[4], wv3[4];
        #pragma unroll
        for (int jj = 0; jj < 4; ++jj) {
            int q = jj ^ swz;
            wv0[jj] = wlds4[(r * 4 + 0) * 128 + seg * 4 + q];
            wv1[jj] = wlds4[(r * 4 + 1) * 128 + seg * 4 + q];
            wv2[jj] = wlds4[(r * 4 + 2) * 128 + seg * 4 + q];
            wv3[jj] = wlds4[(r * 4 + 3) * 128 + seg * 4 + q];
        }

        if (tid < 64) {                    // wave 0: poll + stage h_{t-1}
            const unsigned need = (unsigned)t;
            const unsigned long long* src = hdq + (size_t)sp * 512 + tid;
            unsigned long long v0, v1, v2, v3, v4, v5, v6, v7;
            int guard = 0;
            bool ok = false;
            do {
                v0 = __hip_atomic_load(src,       __ATOMIC_RELAXED, __HIP_MEMORY_SCOPE_AGENT);
                v1 = __hip_atomic_load(src + 64,  __ATOMIC_RELAXED, __HIP_MEMORY_SCOPE_AGENT);
                v2 = __hip_atomic_load(src + 128, __ATOMIC_RELAXED, __HIP_MEMORY_SCOPE_AGENT);
                v3 = __hip_atomic_load(src + 192, __ATOMIC_RELAXED, __HIP_MEMORY_SCOPE_AGENT);
                v4 = __hip_atomic_load(src + 256, __ATOMIC_RELAXED, __HIP_MEMORY_SCOPE_AGENT);
                v5 = __hip_atomic_load(src + 320, __ATOMIC_RELAXED, __HIP_MEMORY_SCOPE_AGENT);
                v6 = __hip_atomic_load(src + 384, __ATOMIC_RELAXED, __HIP_MEMORY_SCOPE_AGENT);
                v7 = __hip_atomic_load(src + 448, __ATOMIC_RELAXED, __HIP_MEMORY_SCOPE_AGENT);
                ok = ((unsigned)(v0 >> 32) == need) & ((unsigned)(v1 >> 32) == need)
                   & ((unsigned)(v2 >> 32) == need) & ((unsigned)(v3 >> 32) == need)
                   & ((unsigned)(v4 >> 32) == need) & ((unsigned)(v5 >> 32) == need)
                   & ((unsigned)(v6 >> 32) == need) & ((unsigned)(v7 >> 32) == need);
            } while (!ok && ++guard < (1 << 20));
            hl[sp][tid]       = __uint_as_float((unsigned)v0);
            hl[sp][tid + 64]  = __uint_as_float((unsigned)v1);
            hl[sp][tid + 128] = __uint_as_float((unsigned)v2);
            hl[sp][tid + 192] = __uint_as_float((unsigned)v3);
            hl[sp][tid + 256] = __uint_as_float((unsigned)v4);
            hl[sp][tid + 320] = __uint_as_float((unsigned)v5);
            hl[sp][tid + 384] = __uint_as_float((unsigned)v6);
            hl[sp][tid + 448] = __uint_as_float((unsigned)v7);
        }
        __syncthreads();

        // 4 gates x 16-float chunk; h reads swizzle-matched to w prefetch
        float a0 = 0.f, a1 = 0.f, a2 = 0.f, a3 = 0.f;
        #pragma unroll
        for (int jj = 0; jj < 4; ++jj) {
            int q = jj ^ swz;
            float4 hv = hl4[sp * 128 + seg * 4 + q];
            a0 = fmaf(wv0[jj].x, hv.x, a0); a0 = fmaf(wv0[jj].y, hv.y, a0);
            a0 = fmaf(wv0[jj].z, hv.z, a0); a0 = fmaf(wv0[jj].w, hv.w, a0);
            a1 = fmaf(wv1[jj].x, hv.x, a1); a1 = fmaf(wv1[jj].y, hv.y, a1);
            a1 = fmaf(wv1[jj].z, hv.z, a1); a1 = fmaf(wv1[jj].w, hv.w, a1);
            a2 = fmaf(wv2[jj].x, hv.x, a2); a2 = fmaf(wv2[jj].y, hv.y, a2);
            a2 = fmaf(wv2[jj].z, hv.z, a2); a2 = fmaf(wv2[jj].w, hv.w, a2);
            a3 = fmaf(wv3[jj].x, hv.x, a3); a3 = fmaf(wv3[jj].y, hv.y, a3);
            a3 = fmaf(wv3[jj].z, hv.z, a3); a3 = fmaf(wv3[jj].w, hv.w, a3);
        }
        #pragma unroll
        for (int m = 1; m < 32; m <<= 1) {
            a0 += __shfl_xor(a0, m);
            a1 += __shfl_xor(a1, m);
            a2 += __shfl_xor(a2, m);
            a3 += __shfl_xor(a3, m);
        }

        if (seg == 0) {
            float ff  = sigm(a0 + gx4.x);
            float iiv = sigm(a1 + gx4.y);
            float ccv = tanh_fast(a2 + gx4.z);
            float ov  = sigm(a3 + gx4.w);
            cold = fmaf(ff, cold, iiv * ccv);
            float hnew = tanh_fast(cold) * ov;
            unsigned long long tv = ((unsigned long long)(unsigned)(t + 1) << 32)
                                  | (unsigned long long)__float_as_uint(hnew);
            atomicExch(hdq + (size_t)sc * 512 + b * 8 + r, tv);
            if (t == T_TOTAL - 1) {
                out[b * 8 + r]       = cold;
                out[512 + b * 8 + r] = hnew;
            }
        }
    }

    if (seg == 0) cstate[b * 8 + r] = cold;
}

// ---------------------------------------------------------------------------
extern "C" void kernel_launch(void* const* d_in, const int* in_sizes, int n_in,
                              void* d_out, int out_size, void* d_ws, size_t ws_size,
                              hipStream_t stream)
{
    const float* x  = (const float*)d_in[0];
    const float* wf = (const float*)d_in[1];
    const float* bf = (const float*)d_in[2];
    const float* wi = (const float*)d_in[3];
    const float* bi = (const float*)d_in[4];
    const float* wc = (const float*)d_in[5];
    const float* bc = (const float*)d_in[6];
    const float* wo = (const float*)d_in[7];
    const float* bo = (const float*)d_in[8];
    float* out = (float*)d_out;

    char* wsb = (char*)d_ws;
    unsigned long long* hdq = (unsigned long long*)wsb;      // 2*512*8 = 8192 B
    float* cst = (float*)(wsb + 8192);                       // 512*4   = 2048 B
    const size_t metaBytes = 8192 + 2048;                    // 10240 (16B aligned)
    float* gxbuf = (float*)(wsb + metaBytes);

    size_t gxCapSteps = (ws_size > metaBytes)
                        ? (ws_size - metaBytes) / (2048 * sizeof(float)) : 0;
    int CH = (gxCapSteps < (size_t)T_TOTAL) ? (int)gxCapSteps : T_TOTAL;
    CH &= ~15;
    if (CH < 16) CH = 16;

    hipMemsetAsync(wsb, 0, metaBytes, stream);   // tags=0 (t=0 poll passes), c=0, h=0

    for (int t0 = 0; t0 < T_TOTAL; t0 += CH) {
        int tend  = t0 + CH; if (tend > T_TOTAL) tend = T_TOTAL;
        int steps = tend - t0;
        dim3 ggrid((steps + 15) / 16, 16);
        lstm_gemm_x<<<ggrid, 256, 0, stream>>>(x, wf, wi, wc, wo,
                                               bf, bi, bc, bo, gxbuf, t0, tend);
        lstm_serial<<<NBLK, 256, 0, stream>>>(wf, wi, wc, wo, gxbuf,
                                              hdq, cst, t0, steps, out);
    }
}